// Round 2
// baseline (682.388 us; speedup 1.0000x reference)
//
#include <hip/hip_runtime.h>

#define BB 64
#define SS 2048
#define HH 1024
#define CHUNK 128                 // S-rows per block
#define NCHUNK (SS / CHUNK)       // 16 chunks per batch
#define ROWS_PER_WAVE (CHUNK / 4) // 32 rows per wave

// p = exp(tanh(t)) without branches:
//   tanh(t) = 1 - 2/(1+exp(2t));  p = e * exp(-2/(1+exp(2t)))
__device__ __forceinline__ float exp_tanh(float t) {
    float a  = __expf(2.0f * t);
    float r2 = 2.0f * __builtin_amdgcn_rcpf(1.0f + a);
    return 2.71828182845904523f * __expf(-r2);
}

// Pass 1: per (batch, chunk) block compute p_s = exp(tanh(x_s.w + b)) and
// partial context  ctx_c[h] = sum_{s in chunk} p_s * x[s,h], single read of x.
__global__ __launch_bounds__(256) void attn_pass1(
    const float* __restrict__ x,      // [B,S,H]
    const float* __restrict__ w,      // [H]
    const float* __restrict__ bias,   // [1]
    float*       p_out,               // [B,S]  (weights region of d_out, reused)
    float* __restrict__ ctx_part,     // [B*NCHUNK, H]
    float* __restrict__ d_part)       // [B*NCHUNK*4]
{
    const int blk  = blockIdx.x;       // 0 .. B*NCHUNK-1
    const int b    = blk >> 4;         // / NCHUNK
    const int c    = blk & (NCHUNK - 1);
    const int tid  = threadIdx.x;
    const int wave = tid >> 6;
    const int lane = tid & 63;

    const float bval = bias[0];

    // per-lane weight fragment: h = lane*4 + i*256 covers all 1024 columns
    float4 wv[4];
#pragma unroll
    for (int i = 0; i < 4; ++i)
        wv[i] = *reinterpret_cast<const float4*>(w + lane * 4 + i * 256);

    const int s0 = c * CHUNK + wave * ROWS_PER_WAVE;
    const float* xb = x + ((size_t)b * SS + (size_t)s0) * HH;

    float4 acc[4];
#pragma unroll
    for (int i = 0; i < 4; ++i) acc[i] = make_float4(0.f, 0.f, 0.f, 0.f);
    float dsum = 0.f;   // NOTE: identical across all 64 lanes after row reduce
    float pr   = 0.f;   // lane r keeps p of row r (r < 32)

#pragma unroll 2
    for (int r = 0; r < ROWS_PER_WAVE; ++r) {
        const float* row = xb + (size_t)r * HH;
        float4 xv[4];
#pragma unroll
        for (int i = 0; i < 4; ++i)
            xv[i] = *reinterpret_cast<const float4*>(row + lane * 4 + i * 256);

        // dot(x_row, w) — per-lane partial
        float t = 0.f;
#pragma unroll
        for (int i = 0; i < 4; ++i) {
            t = fmaf(xv[i].x, wv[i].x, t);
            t = fmaf(xv[i].y, wv[i].y, t);
            t = fmaf(xv[i].z, wv[i].z, t);
            t = fmaf(xv[i].w, wv[i].w, t);
        }
        // 64-lane butterfly reduce: afterwards EVERY lane holds the full dot
#pragma unroll
        for (int off = 32; off > 0; off >>= 1)
            t += __shfl_xor(t, off, 64);
        t += bval;

        float p = exp_tanh(t);          // in [e^-1, e] — no max needed
        pr = (lane == r) ? p : pr;
        dsum += p;                      // full p added on every lane

        // reuse row already in registers for the context partial
#pragma unroll
        for (int i = 0; i < 4; ++i) {
            acc[i].x = fmaf(p, xv[i].x, acc[i].x);
            acc[i].y = fmaf(p, xv[i].y, acc[i].y);
            acc[i].z = fmaf(p, xv[i].z, acc[i].z);
            acc[i].w = fmaf(p, xv[i].w, acc[i].w);
        }
    }

    // coalesced store of the 32 p-values of this wave
    if (lane < ROWS_PER_WAVE)
        p_out[(size_t)b * SS + s0 + lane] = pr;

    // dsum is ALREADY the full wave partial (identical on every lane) —
    // do NOT reduce again (previous round's 64x bug). Lane 0 writes it.
    if (lane == 0) d_part[blk * 4 + wave] = dsum;

    // combine 4 waves' context partials through LDS
    __shared__ float lds[4 * HH];     // 16 KiB
#pragma unroll
    for (int i = 0; i < 4; ++i)
        *reinterpret_cast<float4*>(&lds[wave * HH + lane * 4 + i * 256]) = acc[i];
    __syncthreads();

    const int h = tid * 4;            // 256 threads * 4 = 1024
    float4 v0 = *reinterpret_cast<float4*>(&lds[0 * HH + h]);
    float4 v1 = *reinterpret_cast<float4*>(&lds[1 * HH + h]);
    float4 v2 = *reinterpret_cast<float4*>(&lds[2 * HH + h]);
    float4 v3 = *reinterpret_cast<float4*>(&lds[3 * HH + h]);
    float4 s;
    s.x = (v0.x + v1.x) + (v2.x + v3.x);
    s.y = (v0.y + v1.y) + (v2.y + v3.y);
    s.z = (v0.z + v1.z) + (v2.z + v3.z);
    s.w = (v0.w + v1.w) + (v2.w + v3.w);
    *reinterpret_cast<float4*>(&ctx_part[(size_t)blk * HH + h]) = s;
}

// Pass 2: per batch, D = sum of 64 wave-partials; context = (sum of 16 chunk
// partials)/D; weights = p/D (in place over the p values in d_out).
__global__ __launch_bounds__(256) void attn_pass2(
    const float* p_in,                 // aliases d_out weights region
    const float* __restrict__ ctx_part,
    const float* __restrict__ d_part,
    float*       out)                  // d_out: [B*H] context, then [B*S] weights
{
    const int b   = blockIdx.x;
    const int q   = blockIdx.y;        // 0..3
    const int tid = threadIdx.x;

    __shared__ float sD;
    float d = (tid < 64) ? d_part[b * 64 + tid] : 0.f;
    if (tid < 64) {
#pragma unroll
        for (int off = 32; off > 0; off >>= 1)
            d += __shfl_xor(d, off, 64);
        if (tid == 0) sD = d;
    }
    __syncthreads();
    const float invD = 1.0f / sD;

    // context: this block handles h in [q*256, q*256+256)
    const int h = q * 256 + tid;
    float sum = 0.f;
#pragma unroll
    for (int c2 = 0; c2 < NCHUNK; ++c2)
        sum += ctx_part[((size_t)b * NCHUNK + c2) * HH + h];
    out[(size_t)b * HH + h] = sum * invD;

    // weights: this block handles s in [q*512, q*512+512)
    const int sbase = q * 512;
#pragma unroll
    for (int k = 0; k < 2; ++k) {
        const int s = sbase + k * 256 + tid;
        const float p = p_in[(size_t)b * SS + s];
        out[(size_t)BB * HH + (size_t)b * SS + s] = p * invD;
    }
}

extern "C" void kernel_launch(void* const* d_in, const int* in_sizes, int n_in,
                              void* d_out, int out_size, void* d_ws, size_t ws_size,
                              hipStream_t stream) {
    const float* x    = (const float*)d_in[0];  // rnn_output [B,S,H]
    const float* w    = (const float*)d_in[1];  // attn_w [H]
    const float* bias = (const float*)d_in[2];  // attn_b [1]
    float* out = (float*)d_out;

    // d_out layout: context [B*H] then weights [B*S]; stash p in the weights
    // region so pass2 can rescale in place.
    float* p_out = out + (size_t)BB * HH;

    float* ctx_part = (float*)d_ws;                              // B*16*1024 f32 = 4 MiB
    float* d_part   = ctx_part + (size_t)BB * NCHUNK * HH;       // 4096 f32

    attn_pass1<<<dim3(BB * NCHUNK), 256, 0, stream>>>(x, w, bias, p_out, ctx_part, d_part);
    attn_pass2<<<dim3(BB, 4), 256, 0, stream>>>(p_out, ctx_part, d_part, out);
}